// Round 2
// baseline (457.806 us; speedup 1.0000x reference)
//
#include <hip/hip_runtime.h>
#include <stdint.h>

#define D_DIM 256
#define NPAD  640   // 256 (W_lin) + 256 (W_res) + 8 (att_l) + 8 (att_r) + 112 zero pad -> 5 x 128 tiles

typedef __bf16 bf16x8 __attribute__((ext_vector_type(8)));
typedef float  f32x4  __attribute__((ext_vector_type(4)));

__device__ __forceinline__ float bf2f(unsigned short u) {
  union { unsigned int i; float f; } cv; cv.i = ((unsigned int)u) << 16; return cv.f;
}
__device__ __forceinline__ unsigned short f2bf(float f) {
  union { float f; unsigned int i; } cv; cv.f = f;
  unsigned int i = cv.i;
  unsigned int lsb = (i >> 16) & 1u;
  i += 0x7fffu + lsb;   // round-to-nearest-even
  return (unsigned short)(i >> 16);
}
__device__ __forceinline__ void gld16(const void* gptr, void* lptr) {
  __builtin_amdgcn_global_load_lds(
      (const __attribute__((address_space(1))) unsigned int*)gptr,
      (__attribute__((address_space(3))) unsigned int*)lptr, 16, 0, 0);
}

// ---------------- setup: [cvt_feat | prep_bt] by block range ----------------
__global__ __launch_bounds__(256) void setup_cvt_prep(
    const float* __restrict__ feat, unsigned short* __restrict__ fb,
    const float* __restrict__ W_lin, const float* __restrict__ W_res,
    const float* __restrict__ att_l, const float* __restrict__ att_r,
    unsigned short* __restrict__ Bt, int nelem, int nb_cvt) {
  int bid = blockIdx.x, t = threadIdx.x;
  if (bid < nb_cvt) {
    int i = (bid * 256 + t) * 8;
    if (i >= nelem) return;
    float4 v0 = *(const float4*)(feat + i);
    float4 v1 = *(const float4*)(feat + i + 4);
    ushort4 a, b;
    a.x = f2bf(v0.x); a.y = f2bf(v0.y); a.z = f2bf(v0.z); a.w = f2bf(v0.w);
    b.x = f2bf(v1.x); b.y = f2bf(v1.y); b.z = f2bf(v1.z); b.w = f2bf(v1.w);
    *(ushort4*)(fb + i) = a;
    *(ushort4*)(fb + i + 4) = b;
  } else {
    int idx = (bid - nb_cvt) * 256 + t;   // covers NPAD*D_DIM exactly
    int n = idx >> 8, k = idx & 255;
    float v = 0.f;
    if (n < 256) v = W_lin[k * 256 + n];
    else if (n < 512) v = W_res[k * 256 + (n - 256)];
    else if (n < 520) {
      int h = n - 512; float s = 0.f;
      #pragma unroll
      for (int c = 0; c < 32; ++c) s += W_lin[k * 256 + h * 32 + c] * att_l[h * 32 + c];
      v = s;
    } else if (n < 528) {
      int h = n - 520; float s = 0.f;
      #pragma unroll
      for (int c = 0; c < 32; ++c) s += W_lin[k * 256 + h * 32 + c] * att_r[h * 32 + c];
      v = s;
    }
    Bt[idx] = f2bf(v);
  }
}

// ---------------- scans ----------------
__global__ __launch_bounds__(256) void scan_partial(const int* __restrict__ cnt,
                                                    int* __restrict__ bsum, int N) {
  __shared__ int s[256];
  int t = threadIdx.x;
  int i = blockIdx.x * 256 + t;
  s[t] = (i < N) ? cnt[i] : 0;
  __syncthreads();
  for (int off = 128; off > 0; off >>= 1) {
    if (t < off) s[t] += s[t + off];
    __syncthreads();
  }
  if (t == 0) bsum[blockIdx.x] = s[0];
}

__global__ __launch_bounds__(256) void scan_top(int* __restrict__ bsum, int nb) {
  __shared__ int s[256];
  int t = threadIdx.x;
  int v = (t < nb) ? bsum[t] : 0;
  s[t] = v;
  __syncthreads();
  for (int off = 1; off < 256; off <<= 1) {
    int u = (t >= off) ? s[t - off] : 0;
    __syncthreads();
    s[t] += u;
    __syncthreads();
  }
  if (t < nb) bsum[t] = s[t] - v;   // exclusive
}

__global__ __launch_bounds__(256) void scan_apply(const int* __restrict__ cnt,
                                                  const int* __restrict__ bsum,
                                                  int* __restrict__ row_ptr, int N) {
  __shared__ int s[256];
  int t = threadIdx.x;
  int i = blockIdx.x * 256 + t;
  int v = (i < N) ? cnt[i] : 0;
  s[t] = v;
  __syncthreads();
  for (int off = 1; off < 256; off <<= 1) {
    int u = (t >= off) ? s[t - off] : 0;
    __syncthreads();
    s[t] += u;
    __syncthreads();
  }
  int excl = bsum[blockIdx.x] + s[t] - v;
  if (i < N) {
    row_ptr[i] = excl;
    if (i == N - 1) row_ptr[N] = excl + v;
  }
}

// ---------------- fused [hist | bf16 MFMA GEMM] ----------------
// blocks [0, nb_hist): edge histogram + rank (random atomics, latency-bound) —
// placed FIRST so they overlap the entire GEMM phase. blocks >= nb_hist: GEMM tiles.
__global__ __launch_bounds__(256) void gemm_hist(
    const unsigned short* __restrict__ A,   // feat bf16 [M][256]
    const unsigned short* __restrict__ Bt,  // [640][256]
    float* __restrict__ out, unsigned short* __restrict__ xbf,
    float* __restrict__ alpha_l, float* __restrict__ alpha_r, int M,
    const int* __restrict__ dst, int* __restrict__ cnt, int* __restrict__ rank,
    int E, int nb_hist, int gx) {
  __shared__ unsigned short As[128 * 32];
  __shared__ unsigned short Bs[128 * 32];

  if ((int)blockIdx.x < nb_hist) {
    int base = (int)blockIdx.x * 2048 + threadIdx.x;
    #pragma unroll
    for (int u = 0; u < 8; ++u) {
      int e = base + u * 256;
      if (e < E) rank[e] = atomicAdd(&cnt[dst[e]], 1);   // 8 independent RMWs in flight
    }
    return;
  }

  int tid  = threadIdx.x;
  int w    = tid >> 6, lane = tid & 63;
  int gb   = (int)blockIdx.x - nb_hist;
  int bm   = (gb % gx) * 128, bn = (gb / gx) * 128;
  int wm   = (w & 1) * 64, wn = (w >> 1) * 64;
  int l16  = lane & 15, quad = lane >> 4;

  f32x4 acc[4][4] = {};

  int srow = w * 32 + (lane >> 2);   // staging row (+ i*16)
  int koff = (lane & 3) * 8;         // staging k offset (elements)

  for (int k0 = 0; k0 < 256; k0 += 32) {
    #pragma unroll
    for (int i = 0; i < 2; ++i) {
      int r  = srow + i * 16;
      int rg = bm + r; if (rg > M - 1) rg = M - 1;          // clamp (stores guarded)
      gld16(A  + (size_t)rg * 256 + k0 + koff, &As[(w * 32 + i * 16) * 32]);
      gld16(Bt + (size_t)(bn + r) * 256 + k0 + koff, &Bs[(w * 32 + i * 16) * 32]);
    }
    __syncthreads();
    bf16x8 a[4], b[4];
    #pragma unroll
    for (int mi = 0; mi < 4; ++mi)
      a[mi] = *(const bf16x8*)&As[(wm + mi * 16 + l16) * 32 + quad * 8];
    #pragma unroll
    for (int ni = 0; ni < 4; ++ni)
      b[ni] = *(const bf16x8*)&Bs[(wn + ni * 16 + l16) * 32 + quad * 8];
    #pragma unroll
    for (int mi = 0; mi < 4; ++mi)
      #pragma unroll
      for (int ni = 0; ni < 4; ++ni)
        acc[mi][ni] = __builtin_amdgcn_mfma_f32_16x16x32_bf16(a[mi], b[ni], acc[mi][ni], 0, 0, 0);
    __syncthreads();
  }

  #pragma unroll
  for (int mi = 0; mi < 4; ++mi) {
    #pragma unroll
    for (int r = 0; r < 4; ++r) {
      int row = bm + wm + mi * 16 + quad * 4 + r;
      if (row >= M) continue;
      #pragma unroll
      for (int ni = 0; ni < 4; ++ni) {
        int n = bn + wn + ni * 16 + l16;
        float v = acc[mi][ni][r];
        if (n < 256)      xbf[(size_t)row * 256 + n] = f2bf(v);
        else if (n < 512) out[(size_t)row * 256 + (n - 256)] = v;
        else if (n < 520) alpha_l[row * 8 + (n - 512)] = v;
        else if (n < 528) alpha_r[row * 8 + (n - 520)] = v;
      }
    }
  }
}

// ---------------- scatter v2: rank-based placement + score precompute ----------------
// Moves the alpha_l[src]/alpha_r[dst] gathers, leaky_relu and exp OUT of agg's serial
// per-node loop into this edge-parallel (latency-tolerant) kernel. Stores per-(edge,head)
// softmax numerators p as bf16x8 (16 B) at the dst-sorted position, plus src id (4 B).
// Precision: alpha itself already carries ~0.4% bf16-GEMM error (exp-amplified ~3% on p),
// so bf16-rounding p (±0.4%) is negligible vs the existing error budget.
__global__ __launch_bounds__(256) void scatter_kernel(
    const int* __restrict__ eidx, const float* __restrict__ ew,
    const int* __restrict__ row_ptr, const int* __restrict__ rank,
    const float* __restrict__ alpha_l, const float* __restrict__ alpha_r,
    int* __restrict__ srcA, unsigned short* __restrict__ pexp, int E) {
  int e = blockIdx.x * 256 + threadIdx.x;
  if (e >= E) return;
  int s = eidx[e], d = eidx[E + e];
  int pos = row_ptr[d] + rank[e];
  float w = ew[e];
  float4 al0 = *(const float4*)(alpha_l + (size_t)s * 8);
  float4 al1 = *(const float4*)(alpha_l + (size_t)s * 8 + 4);
  float4 ar0 = *(const float4*)(alpha_r + (size_t)d * 8);
  float4 ar1 = *(const float4*)(alpha_r + (size_t)d * 8 + 4);
  float a[8] = {al0.x + ar0.x, al0.y + ar0.y, al0.z + ar0.z, al0.w + ar0.w,
                al1.x + ar1.x, al1.y + ar1.y, al1.z + ar1.z, al1.w + ar1.w};
  ushort4 o0, o1;
  unsigned short pb[8];
  #pragma unroll
  for (int h = 0; h < 8; ++h) {
    float v = w * a[h];
    v = (v > 0.f) ? v : 0.2f * v;        // leaky_relu(0.2)
    pb[h] = f2bf(__expf(v));             // softmax numerator (scores bounded, no max-shift)
  }
  o0.x = pb[0]; o0.y = pb[1]; o0.z = pb[2]; o0.w = pb[3];
  o1.x = pb[4]; o1.y = pb[5]; o1.z = pb[6]; o1.w = pb[7];
  srcA[pos] = s;
  *(ushort4*)(pexp + (size_t)pos * 8) = o0;
  *(ushort4*)(pexp + (size_t)pos * 8 + 4) = o1;
}

// ---------------- agg v3: 2 waves per dst node, gather-only serial loop ----------------
// Round-1 lesson: compiler re-serializes source-level ILP pipelining (null). This version
// adds memory-level parallelism structurally: (1) the only random dependent load left in
// the loop is the coalesced 512 B xbf row (p and src are sequential streams), (2) each
// node's edge list is split across 2 waves (interleaved 4-edge groups) -> 2x independent
// gather streams per node + half the serial chain depth; LDS combine at the end.
__global__ __launch_bounds__(256) void agg_kernel(
    const int* __restrict__ row_ptr, const int* __restrict__ srcA,
    const unsigned short* __restrict__ pexp,
    const unsigned short* __restrict__ xbf, float* __restrict__ out, int N) {
  __shared__ float red[2][64][6];        // [node-in-block][lane][l,ac0..3] (+pad)
  int nin  = threadIdx.x >> 7;           // node within block
  int wv   = (threadIdx.x >> 6) & 1;     // wave within node
  int lane = threadIdx.x & 63;
  int node = blockIdx.x * 2 + nin;
  bool active = node < N;
  int h  = lane >> 3;                    // head for this lane's 4 channels
  int cb = lane << 2;                    // channel base (0..252)

  float l = 0.f, ac0 = 0.f, ac1 = 0.f, ac2 = 0.f, ac3 = 0.f;

  if (active) {
    int beg = row_ptr[node], end = row_ptr[node + 1];
    if (beg < end) {
      int last = end - 1;
      const unsigned short* xb = xbf + cb;
      for (int jg = beg + wv * 4; jg < end; jg += 8) {
        int s[4]; float pv[4];
        #pragma unroll
        for (int u = 0; u < 4; ++u) {
          int t = jg + u; t = (t < last) ? t : last;   // clamp (masked below)
          s[u]  = srcA[t];
          pv[u] = bf2f(pexp[(size_t)t * 8 + h]);
        }
        ushort4 xv[4];
        #pragma unroll
        for (int u = 0; u < 4; ++u)
          xv[u] = *(const ushort4*)(xb + ((size_t)s[u] << 8));
        #pragma unroll
        for (int u = 0; u < 4; ++u) {
          float p = (jg + u < end) ? pv[u] : 0.f;      // mask tail
          l += p;
          ac0 = fmaf(p, bf2f(xv[u].x), ac0);
          ac1 = fmaf(p, bf2f(xv[u].y), ac1);
          ac2 = fmaf(p, bf2f(xv[u].z), ac2);
          ac3 = fmaf(p, bf2f(xv[u].w), ac3);
        }
      }
    }
  }

  if (wv == 1) {
    red[nin][lane][0] = l;
    red[nin][lane][1] = ac0; red[nin][lane][2] = ac1;
    red[nin][lane][3] = ac2; red[nin][lane][4] = ac3;
  }
  __syncthreads();
  if (active && wv == 0) {
    l   += red[nin][lane][0];
    ac0 += red[nin][lane][1]; ac1 += red[nin][lane][2];
    ac2 += red[nin][lane][3]; ac3 += red[nin][lane][4];
    float r = 1.0f / (l + 1e-16f);
    float o0 = ac0 * r, o1 = ac1 * r, o2 = ac2 * r, o3 = ac3 * r;
    o0 = (o0 > 0.f) ? o0 : expm1f(o0);  // elu
    o1 = (o1 > 0.f) ? o1 : expm1f(o1);
    o2 = (o2 > 0.f) ? o2 : expm1f(o2);
    o3 = (o3 > 0.f) ? o3 : expm1f(o3);
    float4* op = (float4*)(out + ((size_t)node << 8) + cb);
    float4 res = *op;                    // residual written by gemm epilogue
    res.x += o0; res.y += o1; res.z += o2; res.w += o3;
    *op = res;
  }
}

extern "C" void kernel_launch(void* const* d_in, const int* in_sizes, int n_in,
                              void* d_out, int out_size, void* d_ws, size_t ws_size,
                              hipStream_t stream) {
  const float* feat  = (const float*)d_in[0];
  const float* ew    = (const float*)d_in[1];
  const float* W_lin = (const float*)d_in[2];
  const float* att_l = (const float*)d_in[3];
  const float* att_r = (const float*)d_in[4];
  const float* W_res = (const float*)d_in[5];
  const int*   eidx  = (const int*)d_in[6];
  float* out = (float*)d_out;

  int N = in_sizes[0] / D_DIM;
  int E = in_sizes[1];

  char* p = (char*)d_ws;
  auto alloc = [&](size_t bytes) {
    char* r = p; p += (bytes + 255) & ~(size_t)255; return r;
  };
  unsigned short* xbf  = (unsigned short*)alloc((size_t)N * 256 * 2);   // 25.6 MB
  unsigned short* fb   = (unsigned short*)alloc((size_t)N * 256 * 2);   // 25.6 MB
  float* alpha_l       = (float*)alloc((size_t)N * 8 * 4);
  float* alpha_r       = (float*)alloc((size_t)N * 8 * 4);
  unsigned short* Bt   = (unsigned short*)alloc((size_t)NPAD * D_DIM * 2);
  int*   row_ptr       = (int*)alloc((size_t)(N + 1) * 4);
  int*   cnt           = (int*)alloc((size_t)N * 4);
  int*   rank          = (int*)alloc((size_t)E * 4);
  int*   bsum          = (int*)alloc(1024);
  int*   srcA          = (int*)alloc((size_t)E * 4);                    // 6.4 MB
  unsigned short* pexp_sep = (unsigned short*)alloc((size_t)E * 8 * 2); // 25.6 MB
  bool sep_ok = ((size_t)((char*)(pexp_sep + (size_t)E * 8) - (char*)d_ws) <= ws_size);
  // fallback: alias pexp onto fb (fb dead after gemm; scatter runs after gemm)
  unsigned short* pexp = sep_ok ? pexp_sep : fb;

  int nb      = (N + 255) / 256;
  int nb_cvt  = (N * 256 / 8 + 255) / 256;
  int nb_prep = NPAD * D_DIM / 256;
  int nb_hist = (E + 2047) / 2048;    // 8 edges/thread
  int nb_scat = (E + 255) / 256;
  int gx = (N + 127) / 128;
  int gemm_blocks = gx * (NPAD / 128);

  hipMemsetAsync(cnt, 0, (size_t)N * 4, stream);

  setup_cvt_prep<<<nb_cvt + nb_prep, 256, 0, stream>>>(
      feat, fb, W_lin, W_res, att_l, att_r, Bt, N * 256, nb_cvt);

  gemm_hist<<<nb_hist + gemm_blocks, 256, 0, stream>>>(
      fb, Bt, out, xbf, alpha_l, alpha_r, N,
      eidx + E, cnt, rank, E, nb_hist, gx);

  scan_partial<<<nb, 256, 0, stream>>>(cnt, bsum, N);
  scan_top<<<1, 256, 0, stream>>>(bsum, nb);
  scan_apply<<<nb, 256, 0, stream>>>(cnt, bsum, row_ptr, N);

  scatter_kernel<<<nb_scat, 256, 0, stream>>>(
      eidx, ew, row_ptr, rank, alpha_l, alpha_r, srcA, pexp, E);

  agg_kernel<<<(N + 1) / 2, 256, 0, stream>>>(row_ptr, srcA, pexp, xbf, out, N);
}

// Round 3
// 408.727 us; speedup vs baseline: 1.1201x; 1.1201x over previous
//
#include <hip/hip_runtime.h>
#include <stdint.h>

#define D_DIM 256
#define NPAD  640   // 256 (W_lin) + 256 (W_res) + 8 (att_l) + 8 (att_r) + 112 zero pad -> 5 x 128 tiles

typedef __bf16 bf16x8 __attribute__((ext_vector_type(8)));
typedef float  f32x4  __attribute__((ext_vector_type(4)));

__device__ __forceinline__ float bf2f(unsigned short u) {
  union { unsigned int i; float f; } cv; cv.i = ((unsigned int)u) << 16; return cv.f;
}
__device__ __forceinline__ unsigned short f2bf(float f) {
  union { float f; unsigned int i; } cv; cv.f = f;
  unsigned int i = cv.i;
  unsigned int lsb = (i >> 16) & 1u;
  i += 0x7fffu + lsb;   // round-to-nearest-even
  return (unsigned short)(i >> 16);
}
__device__ __forceinline__ void gld16(const void* gptr, void* lptr) {
  __builtin_amdgcn_global_load_lds(
      (const __attribute__((address_space(1))) unsigned int*)gptr,
      (__attribute__((address_space(3))) unsigned int*)lptr, 16, 0, 0);
}

// ---------------- setup: [cvt_feat | prep_bt] by block range ----------------
__global__ __launch_bounds__(256) void setup_cvt_prep(
    const float* __restrict__ feat, unsigned short* __restrict__ fb,
    const float* __restrict__ W_lin, const float* __restrict__ W_res,
    const float* __restrict__ att_l, const float* __restrict__ att_r,
    unsigned short* __restrict__ Bt, int nelem, int nb_cvt) {
  int bid = blockIdx.x, t = threadIdx.x;
  if (bid < nb_cvt) {
    int i = (bid * 256 + t) * 8;
    if (i >= nelem) return;
    float4 v0 = *(const float4*)(feat + i);
    float4 v1 = *(const float4*)(feat + i + 4);
    ushort4 a, b;
    a.x = f2bf(v0.x); a.y = f2bf(v0.y); a.z = f2bf(v0.z); a.w = f2bf(v0.w);
    b.x = f2bf(v1.x); b.y = f2bf(v1.y); b.z = f2bf(v1.z); b.w = f2bf(v1.w);
    *(ushort4*)(fb + i) = a;
    *(ushort4*)(fb + i + 4) = b;
  } else {
    int idx = (bid - nb_cvt) * 256 + t;   // covers NPAD*D_DIM exactly
    int n = idx >> 8, k = idx & 255;
    float v = 0.f;
    if (n < 256) v = W_lin[k * 256 + n];
    else if (n < 512) v = W_res[k * 256 + (n - 256)];
    else if (n < 520) {
      int h = n - 512; float s = 0.f;
      #pragma unroll
      for (int c = 0; c < 32; ++c) s += W_lin[k * 256 + h * 32 + c] * att_l[h * 32 + c];
      v = s;
    } else if (n < 528) {
      int h = n - 520; float s = 0.f;
      #pragma unroll
      for (int c = 0; c < 32; ++c) s += W_lin[k * 256 + h * 32 + c] * att_r[h * 32 + c];
      v = s;
    }
    Bt[idx] = f2bf(v);
  }
}

// ---------------- scans ----------------
__global__ __launch_bounds__(256) void scan_partial(const int* __restrict__ cnt,
                                                    int* __restrict__ bsum, int N) {
  __shared__ int s[256];
  int t = threadIdx.x;
  int i = blockIdx.x * 256 + t;
  s[t] = (i < N) ? cnt[i] : 0;
  __syncthreads();
  for (int off = 128; off > 0; off >>= 1) {
    if (t < off) s[t] += s[t + off];
    __syncthreads();
  }
  if (t == 0) bsum[blockIdx.x] = s[0];
}

__global__ __launch_bounds__(256) void scan_top(int* __restrict__ bsum, int nb) {
  __shared__ int s[256];
  int t = threadIdx.x;
  int v = (t < nb) ? bsum[t] : 0;
  s[t] = v;
  __syncthreads();
  for (int off = 1; off < 256; off <<= 1) {
    int u = (t >= off) ? s[t - off] : 0;
    __syncthreads();
    s[t] += u;
    __syncthreads();
  }
  if (t < nb) bsum[t] = s[t] - v;   // exclusive
}

__global__ __launch_bounds__(256) void scan_apply(const int* __restrict__ cnt,
                                                  const int* __restrict__ bsum,
                                                  int* __restrict__ row_ptr, int N) {
  __shared__ int s[256];
  int t = threadIdx.x;
  int i = blockIdx.x * 256 + t;
  int v = (i < N) ? cnt[i] : 0;
  s[t] = v;
  __syncthreads();
  for (int off = 1; off < 256; off <<= 1) {
    int u = (t >= off) ? s[t - off] : 0;
    __syncthreads();
    s[t] += u;
    __syncthreads();
  }
  int excl = bsum[blockIdx.x] + s[t] - v;
  if (i < N) {
    row_ptr[i] = excl;
    if (i == N - 1) row_ptr[N] = excl + v;
  }
}

// ---------------- fused [hist | bf16 MFMA GEMM] ----------------
// blocks [0, nb_hist): edge histogram + rank (random atomics, latency-bound) —
// placed FIRST so they overlap the entire GEMM phase. blocks >= nb_hist: GEMM tiles.
// v3: BK=64 (4 barrier-phases instead of 8, 32 MFMA/phase) + XOR-swizzled LDS.
// Swizzle discipline (rule #21): global_load_lds writes LINEARLY (base+lane*16),
// so the swizzle is applied by permuting the per-lane GLOBAL source column
// (koff ^ (row&7)) and applying the SAME involution on the ds_read column.
// Without it, BK=64's 128-B row stride would be a 16-way bank conflict.
__global__ __launch_bounds__(256) void gemm_hist(
    const unsigned short* __restrict__ A,   // feat bf16 [M][256]
    const unsigned short* __restrict__ Bt,  // [640][256]
    float* __restrict__ out, unsigned short* __restrict__ xbf,
    float* __restrict__ alpha_l, float* __restrict__ alpha_r, int M,
    const int* __restrict__ dst, int* __restrict__ cnt, int* __restrict__ rank,
    int E, int nb_hist, int gx) {
  __shared__ unsigned short As[128 * 64];
  __shared__ unsigned short Bs[128 * 64];

  if ((int)blockIdx.x < nb_hist) {
    int base = (int)blockIdx.x * 2048 + threadIdx.x;
    #pragma unroll
    for (int u = 0; u < 8; ++u) {
      int e = base + u * 256;
      if (e < E) rank[e] = atomicAdd(&cnt[dst[e]], 1);   // 8 independent RMWs in flight
    }
    return;
  }

  int tid  = threadIdx.x;
  int w    = tid >> 6, lane = tid & 63;
  int gb   = (int)blockIdx.x - nb_hist;
  int bm   = (gb % gx) * 128, bn = (gb / gx) * 128;
  int wm   = (w & 1) * 64, wn = (w >> 1) * 64;
  int l16  = lane & 15, quad = lane >> 4;

  f32x4 acc[4][4] = {};

  int sr8     = lane >> 3;                       // row within 8-row staging group
  int koff_sw = (((lane & 7) ^ sr8) * 8);        // pre-swizzled source column (elements)

  for (int k0 = 0; k0 < 256; k0 += 64) {
    #pragma unroll
    for (int j = 0; j < 4; ++j) {
      int rbase = w * 32 + j * 8;
      int rga = bm + rbase + sr8; if (rga > M - 1) rga = M - 1;   // clamp (stores guarded)
      gld16(A  + (size_t)rga * 256 + k0 + koff_sw, &As[rbase * 64]);
      gld16(Bt + (size_t)(bn + rbase + sr8) * 256 + k0 + koff_sw, &Bs[rbase * 64]);
    }
    __syncthreads();
    #pragma unroll
    for (int kk = 0; kk < 64; kk += 32) {
      bf16x8 a[4], b[4];
      #pragma unroll
      for (int mi = 0; mi < 4; ++mi) {
        int r = wm + mi * 16 + l16;
        int col = (kk * 2 + quad * 16) ^ ((r & 7) << 4);   // byte col, same involution
        a[mi] = *(const bf16x8*)((const char*)&As[r * 64] + col);
      }
      #pragma unroll
      for (int ni = 0; ni < 4; ++ni) {
        int r = wn + ni * 16 + l16;
        int col = (kk * 2 + quad * 16) ^ ((r & 7) << 4);
        b[ni] = *(const bf16x8*)((const char*)&Bs[r * 64] + col);
      }
      #pragma unroll
      for (int mi = 0; mi < 4; ++mi)
        #pragma unroll
        for (int ni = 0; ni < 4; ++ni)
          acc[mi][ni] = __builtin_amdgcn_mfma_f32_16x16x32_bf16(a[mi], b[ni], acc[mi][ni], 0, 0, 0);
    }
    __syncthreads();
  }

  #pragma unroll
  for (int mi = 0; mi < 4; ++mi) {
    #pragma unroll
    for (int r = 0; r < 4; ++r) {
      int row = bm + wm + mi * 16 + quad * 4 + r;
      if (row >= M) continue;
      #pragma unroll
      for (int ni = 0; ni < 4; ++ni) {
        int n = bn + wn + ni * 16 + l16;
        float v = acc[mi][ni][r];
        if (n < 256)      xbf[(size_t)row * 256 + n] = f2bf(v);
        else if (n < 512) out[(size_t)row * 256 + (n - 256)] = v;
        else if (n < 520) alpha_l[row * 8 + (n - 512)] = v;
        else if (n < 528) alpha_r[row * 8 + (n - 520)] = v;
      }
    }
  }
}

// ---------------- scatter (atomic-free, rank-based) — cheap 8 B/edge payload ----------------
// Round-2 lesson: materializing per-(edge,head) exp scores (20 B/edge random scatter +
// double alpha gathers) cost more than it saved in agg. Keep the scatter minimal.
__global__ __launch_bounds__(256) void scatter_kernel(
    const int* __restrict__ eidx, const float* __restrict__ ew,
    const int* __restrict__ row_ptr, const int* __restrict__ rank,
    int2* __restrict__ pairs, int E) {
  int e = blockIdx.x * 256 + threadIdx.x;
  if (e < E) {
    int d = eidx[E + e];
    int pos = row_ptr[d] + rank[e];
    int2 p; p.x = eidx[e]; p.y = __float_as_int(ew[e]);
    pairs[pos] = p;
  }
}

// ---------------- agg v4: 2 waves per dst node (structural MLP), alpha in-loop ----------------
// Round-2 confirmed the 2-wave split + shorter chain is what fixed agg's latency bound
// (agg left top-5). This version keeps that structure but computes alpha+exp in-loop:
// the alpha_l gather is one 32 B line per 4-edge group (8 heads x broadcast), and
// alpha_l (1.6 MB) is L2-resident — cheap. pairs stays the 8 B/edge stream.
__global__ __launch_bounds__(256) void agg_kernel(
    const int* __restrict__ row_ptr, const int2* __restrict__ pairs,
    const float* __restrict__ alpha_l, const float* __restrict__ alpha_r,
    const unsigned short* __restrict__ xbf, float* __restrict__ out, int N) {
  __shared__ float red[2][64][6];        // [node-in-block][lane][l,ac0..3] (+pad)
  int nin  = threadIdx.x >> 7;           // node within block
  int wv   = (threadIdx.x >> 6) & 1;     // wave within node
  int lane = threadIdx.x & 63;
  int node = blockIdx.x * 2 + nin;
  bool active = node < N;
  int h  = lane >> 3;                    // head for this lane's 4 channels
  int cb = lane << 2;                    // channel base (0..252)

  float l = 0.f, ac0 = 0.f, ac1 = 0.f, ac2 = 0.f, ac3 = 0.f;

  if (active) {
    int beg = row_ptr[node], end = row_ptr[node + 1];
    if (beg < end) {
      float arv = alpha_r[node * 8 + h];
      int last = end - 1;
      const unsigned short* xb = xbf + cb;
      for (int jg = beg + wv * 4; jg < end; jg += 8) {
        int2 q[4];
        #pragma unroll
        for (int u = 0; u < 4; ++u) {
          int t = jg + u; t = (t < last) ? t : last;   // clamp (masked below)
          q[u] = pairs[t];
        }
        float al[4];
        #pragma unroll
        for (int u = 0; u < 4; ++u) al[u] = alpha_l[(size_t)q[u].x * 8 + h];
        ushort4 xv[4];
        #pragma unroll
        for (int u = 0; u < 4; ++u)
          xv[u] = *(const ushort4*)(xb + ((size_t)q[u].x << 8));
        #pragma unroll
        for (int u = 0; u < 4; ++u) {
          float a = __int_as_float(q[u].y) * (al[u] + arv);
          a = (a > 0.f) ? a : 0.2f * a;            // leaky_relu(0.2)
          float p = __expf(a);
          p = (jg + u < end) ? p : 0.f;            // mask tail
          l += p;
          ac0 = fmaf(p, bf2f(xv[u].x), ac0);
          ac1 = fmaf(p, bf2f(xv[u].y), ac1);
          ac2 = fmaf(p, bf2f(xv[u].z), ac2);
          ac3 = fmaf(p, bf2f(xv[u].w), ac3);
        }
      }
    }
  }

  if (wv == 1) {
    red[nin][lane][0] = l;
    red[nin][lane][1] = ac0; red[nin][lane][2] = ac1;
    red[nin][lane][3] = ac2; red[nin][lane][4] = ac3;
  }
  __syncthreads();
  if (active && wv == 0) {
    l   += red[nin][lane][0];
    ac0 += red[nin][lane][1]; ac1 += red[nin][lane][2];
    ac2 += red[nin][lane][3]; ac3 += red[nin][lane][4];
    float r = 1.0f / (l + 1e-16f);
    float o0 = ac0 * r, o1 = ac1 * r, o2 = ac2 * r, o3 = ac3 * r;
    o0 = (o0 > 0.f) ? o0 : expm1f(o0);  // elu
    o1 = (o1 > 0.f) ? o1 : expm1f(o1);
    o2 = (o2 > 0.f) ? o2 : expm1f(o2);
    o3 = (o3 > 0.f) ? o3 : expm1f(o3);
    float4* op = (float4*)(out + ((size_t)node << 8) + cb);
    float4 res = *op;                    // residual written by gemm epilogue
    res.x += o0; res.y += o1; res.z += o2; res.w += o3;
    *op = res;
  }
}

extern "C" void kernel_launch(void* const* d_in, const int* in_sizes, int n_in,
                              void* d_out, int out_size, void* d_ws, size_t ws_size,
                              hipStream_t stream) {
  const float* feat  = (const float*)d_in[0];
  const float* ew    = (const float*)d_in[1];
  const float* W_lin = (const float*)d_in[2];
  const float* att_l = (const float*)d_in[3];
  const float* att_r = (const float*)d_in[4];
  const float* W_res = (const float*)d_in[5];
  const int*   eidx  = (const int*)d_in[6];
  float* out = (float*)d_out;

  int N = in_sizes[0] / D_DIM;
  int E = in_sizes[1];

  char* p = (char*)d_ws;
  auto alloc = [&](size_t bytes) {
    char* r = p; p += (bytes + 255) & ~(size_t)255; return r;
  };
  unsigned short* xbf  = (unsigned short*)alloc((size_t)N * 256 * 2);   // 25.6 MB
  unsigned short* fb   = (unsigned short*)alloc((size_t)N * 256 * 2);   // 25.6 MB
  float* alpha_l       = (float*)alloc((size_t)N * 8 * 4);
  float* alpha_r       = (float*)alloc((size_t)N * 8 * 4);
  unsigned short* Bt   = (unsigned short*)alloc((size_t)NPAD * D_DIM * 2);
  int*   row_ptr       = (int*)alloc((size_t)(N + 1) * 4);
  int*   cnt           = (int*)alloc((size_t)N * 4);
  int*   rank          = (int*)alloc((size_t)E * 4);
  int*   bsum          = (int*)alloc(1024);
  int2*  pairs_sep     = (int2*)alloc((size_t)E * 8);                   // 12.8 MB
  bool sep_ok = ((size_t)((char*)(pairs_sep + E) - (char*)d_ws) <= ws_size);
  // fallback: alias pairs onto fb (dead after gemm; scatter runs after gemm)
  int2* pairs = sep_ok ? pairs_sep : (int2*)fb;

  int nb      = (N + 255) / 256;
  int nb_cvt  = (N * 256 / 8 + 255) / 256;
  int nb_prep = NPAD * D_DIM / 256;
  int nb_hist = (E + 2047) / 2048;    // 8 edges/thread
  int nb_scat = (E + 255) / 256;
  int gx = (N + 127) / 128;
  int gemm_blocks = gx * (NPAD / 128);

  hipMemsetAsync(cnt, 0, (size_t)N * 4, stream);

  setup_cvt_prep<<<nb_cvt + nb_prep, 256, 0, stream>>>(
      feat, fb, W_lin, W_res, att_l, att_r, Bt, N * 256, nb_cvt);

  gemm_hist<<<nb_hist + gemm_blocks, 256, 0, stream>>>(
      fb, Bt, out, xbf, alpha_l, alpha_r, N,
      eidx + E, cnt, rank, E, nb_hist, gx);

  scan_partial<<<nb, 256, 0, stream>>>(cnt, bsum, N);
  scan_top<<<1, 256, 0, stream>>>(bsum, nb);
  scan_apply<<<nb, 256, 0, stream>>>(cnt, bsum, row_ptr, N);

  scatter_kernel<<<nb_scat, 256, 0, stream>>>(eidx, ew, row_ptr, rank, pairs, E);

  agg_kernel<<<(N + 1) / 2, 256, 0, stream>>>(row_ptr, pairs, alpha_l, alpha_r, xbf, out, N);
}